// Round 1
// baseline (549.370 us; speedup 1.0000x reference)
//
#include <hip/hip_runtime.h>

// out[b,o,h,w] = sum_{i,j in 5x5} K[o][i*5+j] * xpad[b, h+i-2, w+j-2] + bias[o]
// K[o][t!=12] = W[o][t<12 ? t : t-1];  K[o][12] = -sum_c W[o][c]
// (collapse of the reference's 24 shift-subtract channels + 1x1 conv)

#define H_DIM 512
#define W_DIM 512
#define BATCH 16
#define OUTC 32

#define TILE_W 256
#define TILE_H 4
#define BLOCK_X 64
#define BLOCK_Y 4
#define HALO_W (TILE_W + 4)   // 260 valid cols
#define LDS_W  (TILE_W + 8)   // 264 stride: keeps every row 16B-aligned
#define LDS_H  (TILE_H + 4)   // 8 rows

__global__ __launch_bounds__(64) void pc_prep(const float* __restrict__ W,
                                              float* __restrict__ K) {
    int o = threadIdx.x;
    if (o < OUTC) {
        float s = 0.f;
        #pragma unroll
        for (int c = 0; c < 24; ++c) s += W[o * 24 + c];
        #pragma unroll
        for (int t = 0; t < 25; ++t) {
            float v = (t == 12) ? -s : W[o * 24 + (t < 12 ? t : t - 1)];
            K[o * 25 + t] = v;
        }
    }
}

__global__ __launch_bounds__(256) void pc_conv(const float* __restrict__ x,
                                               const float* __restrict__ K,
                                               const float* __restrict__ bias,
                                               float* __restrict__ out) {
    __shared__ float lds[LDS_H * LDS_W];

    const int b  = blockIdx.z;
    const int h0 = blockIdx.y * TILE_H;
    const int w0 = blockIdx.x * TILE_W;
    const int tx = threadIdx.x;            // 0..63
    const int ty = threadIdx.y;            // 0..3
    const int tid = ty * BLOCK_X + tx;

    const float* xb = x + (size_t)b * H_DIM * W_DIM;

    // ---- stage input tile + 2-halo into LDS (zero-pad at image edges) ----
    for (int idx = tid; idx < LDS_H * HALO_W; idx += BLOCK_X * BLOCK_Y) {
        int r = idx / HALO_W;
        int c = idx - r * HALO_W;
        int gh = h0 - 2 + r;
        int gw = w0 - 2 + c;
        float v = 0.f;
        if ((unsigned)gh < (unsigned)H_DIM && (unsigned)gw < (unsigned)W_DIM)
            v = xb[gh * W_DIM + gw];
        lds[r * LDS_W + c] = v;
    }
    __syncthreads();

    // ---- pull this thread's 5x8 neighborhood (4 pixels wide) into regs ----
    float nb[5][8];
    #pragma unroll
    for (int r = 0; r < 5; ++r) {
        const float4* p = (const float4*)&lds[(ty + r) * LDS_W + 4 * tx];
        float4 a = p[0];
        float4 c = p[1];
        nb[r][0] = a.x; nb[r][1] = a.y; nb[r][2] = a.z; nb[r][3] = a.w;
        nb[r][4] = c.x; nb[r][5] = c.y; nb[r][6] = c.z; nb[r][7] = c.w;
    }

    const int h = h0 + ty;
    const int w = w0 + 4 * tx;
    float* op = out + (size_t)b * OUTC * H_DIM * W_DIM + (size_t)h * W_DIM + w;

    #pragma unroll 1
    for (int o = 0; o < OUTC; ++o) {
        const float* kr = K + o * 25;
        float bb = bias[o];
        float acc0 = bb, acc1 = bb, acc2 = bb, acc3 = bb;
        #pragma unroll
        for (int ki = 0; ki < 5; ++ki) {
            #pragma unroll
            for (int kj = 0; kj < 5; ++kj) {
                float k = kr[ki * 5 + kj];   // wave-uniform -> scalar load
                acc0 += k * nb[ki][kj + 0];
                acc1 += k * nb[ki][kj + 1];
                acc2 += k * nb[ki][kj + 2];
                acc3 += k * nb[ki][kj + 3];
            }
        }
        *(float4*)op = make_float4(acc0, acc1, acc2, acc3);
        op += H_DIM * W_DIM;
    }
}

extern "C" void kernel_launch(void* const* d_in, const int* in_sizes, int n_in,
                              void* d_out, int out_size, void* d_ws, size_t ws_size,
                              hipStream_t stream) {
    const float* x    = (const float*)d_in[0];
    const float* W    = (const float*)d_in[1];
    const float* bias = (const float*)d_in[2];
    float* out = (float*)d_out;
    float* K   = (float*)d_ws;   // 32*25 floats = 3200 B

    pc_prep<<<1, 64, 0, stream>>>(W, K);

    dim3 grid(W_DIM / TILE_W, H_DIM / TILE_H, BATCH);   // 2 x 128 x 16
    dim3 block(BLOCK_X, BLOCK_Y, 1);                    // 64 x 4
    pc_conv<<<grid, block, 0, stream>>>(x, K, bias, out);
}